// Round 6
// baseline (1189.058 us; speedup 1.0000x reference)
//
#include <hip/hip_runtime.h>
#include <math.h>

// ---------------------------------------------------------------------------
// B=4096, IN=10338 (pad 10368), H=1024, OUT=229 (pad 256)
// R6: f16x3 split-MFMA GEMM (R4-proven 3-D grid: XCD owns M-slice),
//     reduce+BN fused into one grid-synced kernel (atomic arrive + spin),
//     all conversions in one kernel. 13 launches total.
// ---------------------------------------------------------------------------

typedef _Float16 half8 __attribute__((ext_vector_type(8)));
typedef _Float16 half4_t __attribute__((ext_vector_type(4)));
typedef float floatx4 __attribute__((ext_vector_type(4)));

#define LO_SCALE 4096.0f
#define LO_INV (1.0f / 4096.0f)
#define IN_C 10338
#define INP_C 10368

__device__ __forceinline__ void gld16(const _Float16* g, _Float16* l) {
  __builtin_amdgcn_global_load_lds(
      (const __attribute__((address_space(1))) void*)g,
      (__attribute__((address_space(3))) void*)l, 16, 0, 0);
}

// C_partial[z] = A[M x Ks] * BT[N x Ks]^T  (f16 hi/lo, lo prescaled by 4096)
// grid (M/128, N/128, S); gid%8 == blockIdx.x%8 -> each XCD owns an M-slice
// (A locality, measured 344 MB vs 705 MB for N-sliced). TAG: 0 big 1 mid 2 head.
template <int TAG>
__global__ __launch_bounds__(256, 2)
void gemm_sk(const _Float16* __restrict__ Ah, const _Float16* __restrict__ Al,
             const _Float16* __restrict__ Bh, const _Float16* __restrict__ Bl,
             float* __restrict__ Cp, int Kld, int Ncols, int Ks,
             size_t partStride) {
  __shared__ _Float16 sAh[2][4096], sAl[2][4096];
  __shared__ _Float16 sBh[2][4096], sBl[2][4096];
  const int tid = threadIdx.x;
  const int wv = tid >> 6, ln = tid & 63;
  const int ln15 = ln & 15, q = ln >> 4;
  const int wr = wv >> 1, wc = wv & 1;
  const int bm0 = blockIdx.x * 128, bn0 = blockIdx.y * 128;
  const int k0 = blockIdx.z * Ks;
  Cp += (size_t)blockIdx.z * partStride;

  // staging: source-permuted so fixed lane->LDS placement yields XOR-swizzle
  const int srow = ln >> 2;
  const int swzw = (ln & 3) ^ (srow & 3) ^ ((srow >> 2) & 3);
  const int ch0 = wv * 2, ch1 = wv * 2 + 1;
  const size_t offA0 = (size_t)(bm0 + ch0 * 16 + srow) * Kld + k0 + swzw * 8;
  const size_t offA1 = (size_t)(bm0 + ch1 * 16 + srow) * Kld + k0 + swzw * 8;
  const size_t offB0 = (size_t)(bn0 + ch0 * 16 + srow) * Kld + k0 + swzw * 8;
  const size_t offB1 = (size_t)(bn0 + ch1 * 16 + srow) * Kld + k0 + swzw * 8;

  // fragment reads: de-swizzle
  const int swzr = (q ^ (ln15 & 3) ^ ((ln15 >> 2) & 3)) * 8;
  const int aoff = (wr * 64 + ln15) * 32 + swzr;
  const int boff = (wc * 64 + ln15) * 32 + swzr;

  floatx4 acc[4][4];
  floatx4 acc2[4][4];
#pragma unroll
  for (int i = 0; i < 4; ++i)
#pragma unroll
    for (int j = 0; j < 4; ++j) {
      acc[i][j] = (floatx4){0.f, 0.f, 0.f, 0.f};
      acc2[i][j] = (floatx4){0.f, 0.f, 0.f, 0.f};
    }

  auto stage = [&](int kt, int buf) {
    gld16(Ah + offA0 + kt, &sAh[buf][ch0 * 512]);
    gld16(Ah + offA1 + kt, &sAh[buf][ch1 * 512]);
    gld16(Al + offA0 + kt, &sAl[buf][ch0 * 512]);
    gld16(Al + offA1 + kt, &sAl[buf][ch1 * 512]);
    gld16(Bh + offB0 + kt, &sBh[buf][ch0 * 512]);
    gld16(Bh + offB1 + kt, &sBh[buf][ch1 * 512]);
    gld16(Bl + offB0 + kt, &sBl[buf][ch0 * 512]);
    gld16(Bl + offB1 + kt, &sBl[buf][ch1 * 512]);
  };

  stage(0, 0);
  int cur = 0;
  for (int kt = 0; kt < Ks; kt += 32) {
    __syncthreads();
    if (kt + 32 < Ks) stage(kt + 32, cur ^ 1);

    const _Float16* pAh = &sAh[cur][aoff];
    const _Float16* pAl = &sAl[cur][aoff];
    const _Float16* pBh = &sBh[cur][boff];
    const _Float16* pBl = &sBl[cur][boff];
    half8 bh[4], bl[4];
#pragma unroll
    for (int ni = 0; ni < 4; ++ni) {
      bh[ni] = *(const half8*)(pBh + ni * 512);
      bl[ni] = *(const half8*)(pBl + ni * 512);
    }
#pragma unroll
    for (int mh = 0; mh < 2; ++mh) {
      half8 ah[2], al[2];
#pragma unroll
      for (int i = 0; i < 2; ++i) {
        ah[i] = *(const half8*)(pAh + (mh * 2 + i) * 512);
        al[i] = *(const half8*)(pAl + (mh * 2 + i) * 512);
      }
#pragma unroll
      for (int i = 0; i < 2; ++i) {
        const int mi = mh * 2 + i;
#pragma unroll
        for (int ni = 0; ni < 4; ++ni) {
          acc[mi][ni] = __builtin_amdgcn_mfma_f32_16x16x32_f16(
              ah[i], bh[ni], acc[mi][ni], 0, 0, 0);
          acc2[mi][ni] = __builtin_amdgcn_mfma_f32_16x16x32_f16(
              ah[i], bl[ni], acc2[mi][ni], 0, 0, 0);
          acc2[mi][ni] = __builtin_amdgcn_mfma_f32_16x16x32_f16(
              al[i], bh[ni], acc2[mi][ni], 0, 0, 0);
        }
      }
    }
    cur ^= 1;
  }

  // C/D layout: col = lane&15, row = (lane>>4)*4 + reg  [m89-verified]
#pragma unroll
  for (int mi = 0; mi < 4; ++mi)
#pragma unroll
    for (int ni = 0; ni < 4; ++ni) {
      const int col = bn0 + wc * 64 + ni * 16 + ln15;
      const int rbase = bm0 + wr * 64 + mi * 16 + q * 4;
#pragma unroll
      for (int r = 0; r < 4; ++r)
        Cp[(size_t)(rbase + r) * Ncols + col] =
            acc[mi][ni][r] + acc2[mi][ni][r] * LO_INV;
    }
}

// ---- all conversions in one kernel ----
// jobs 0..5: W[K][N] fp32 -> WT[Npad][Kpad] f16 hi/lo (32x32 tiles)
// blocks >= splitStart: x fp32 -> padded f16 hi/lo (flat, 2048 elems/block)
struct TJob {
  const float* src;
  _Float16* th;
  _Float16* tl;
  int K, N, Kpad, tK, start;
};
struct CJobs {
  TJob j[6];
  const float* x;
  _Float16* xh;
  _Float16* xl;
  int splitStart;
};

__global__ __launch_bounds__(256)
void convert_all(CJobs J) {
  const int b = blockIdx.x;
  const int tid = threadIdx.x;
  if (b >= J.splitStart) {
    int di = (b - J.splitStart) * 256 + tid;
    int base = di * 8;
    int row = base / INP_C;
    int col0 = base - row * INP_C;
    const float* src = J.x + (size_t)row * IN_C + col0;
    float v[8];
#pragma unroll
    for (int j = 0; j < 8; ++j) v[j] = (col0 + j < IN_C) ? src[j] : 0.f;
    half8 h, l;
#pragma unroll
    for (int j = 0; j < 8; ++j) {
      _Float16 hh = (_Float16)v[j];
      h[j] = hh;
      l[j] = (_Float16)((v[j] - (float)hh) * LO_SCALE);
    }
    *(half8*)(J.xh + base) = h;
    *(half8*)(J.xl + base) = l;
    return;
  }
  int ji = 0;
#pragma unroll
  for (int i = 1; i < 6; ++i)
    if (b >= J.j[i].start) ji = i;
  const TJob job = J.j[ji];
  const int t = b - job.start;
  const int kk0 = (t % job.tK) * 32;
  const int nn0 = (t / job.tK) * 32;

  __shared__ float ts[32][33];
  const int tx = tid & 31, ty = tid >> 5;
#pragma unroll
  for (int r = 0; r < 4; ++r) {
    int kk = kk0 + ty + r * 8;
    int nn = nn0 + tx;
    ts[ty + r * 8][tx] =
        (kk < job.K && nn < job.N) ? job.src[(size_t)kk * job.N + nn] : 0.f;
  }
  __syncthreads();
  const int tw = tid & 7, rw = tid >> 3;
  const int nn = nn0 + rw, kk = kk0 + tw * 4;
  half4_t h, l;
#pragma unroll
  for (int i2 = 0; i2 < 4; ++i2) {
    float v = ts[tw * 4 + i2][rw];
    _Float16 hh = (_Float16)v;
    h[i2] = hh;
    l[i2] = (_Float16)((v - (float)hh) * LO_SCALE);
  }
  size_t o = (size_t)nn * job.Kpad + kk;
  *(half4_t*)(job.th + o) = h;
  *(half4_t*)(job.tl + o) = l;
}

// ---- fused: split-K reduce + bias -> Y + col stats, grid-sync, BN finalize
//      + apply (+res, relu) + f16 hi/lo split. grid (16 colblk, 32 rowbands).
__global__ __launch_bounds__(256)
void reduce_bn_fused(const float* __restrict__ Cp,
                     const float* __restrict__ bias, const float* __restrict__ g,
                     const float* __restrict__ be, const float* __restrict__ res,
                     float* __restrict__ outf, _Float16* __restrict__ oh,
                     _Float16* __restrict__ ol, float* __restrict__ Y,
                     float* __restrict__ psum, float* __restrict__ psq, int S,
                     size_t stride, int* __restrict__ counter, float invM) {
  const int N = 1024;
  const int t = threadIdx.x;
  const int cg = t & 15, rl = t >> 4;
  const int cb = blockIdx.x, rb = blockIdx.y;
  const int col4 = cb * 64 + cg * 4;
  const int r0 = rb * 128;

  // phase 1: assemble Y = sum_z Cpart + bias; per-band column stats
  const floatx4 bs = *(const floatx4*)(bias + col4);
  floatx4 s = {0.f, 0.f, 0.f, 0.f}, qq = {0.f, 0.f, 0.f, 0.f};
  for (int r = r0 + rl; r < r0 + 128; r += 16) {
    size_t i = (size_t)r * N + col4;
    floatx4 v = bs;
    for (int k = 0; k < S; ++k) v += *(const floatx4*)(Cp + k * stride + i);
    *(floatx4*)(Y + i) = v;
    s += v;
    qq += v * v;
  }
  __shared__ floatx4 ls[16][16], lq[16][16];
  ls[rl][cg] = s;
  lq[rl][cg] = qq;
  __syncthreads();
  if (t < 16) {
    floatx4 S4 = {0.f, 0.f, 0.f, 0.f}, Q4 = {0.f, 0.f, 0.f, 0.f};
#pragma unroll
    for (int r = 0; r < 16; ++r) {
      S4 += ls[r][t];
      Q4 += lq[r][t];
    }
    size_t o = (size_t)rb * N + cb * 64 + t * 4;
    *(floatx4*)(psum + o) = S4;
    *(floatx4*)(psq + o) = Q4;
  }
  // grid handshake (all 512 blocks co-resident: tiny kernel, 8 blk/CU cap)
  __threadfence();
  __syncthreads();
  if (t == 0) {
    __hip_atomic_fetch_add(counter, 1, __ATOMIC_ACQ_REL,
                           __HIP_MEMORY_SCOPE_AGENT);
    while (__hip_atomic_load(counter, __ATOMIC_ACQUIRE,
                             __HIP_MEMORY_SCOPE_AGENT) < 512)
      __builtin_amdgcn_s_sleep(8);
  }
  __syncthreads();

  // phase 2: final stats for this block's 64 cols (redundant per-col-block)
  {
    const int cc = cb * 64 + (t & 15) * 4;
    const int pr = t >> 4;
    floatx4 S4 = *(const floatx4*)(psum + (size_t)pr * N + cc);
    S4 += *(const floatx4*)(psum + (size_t)(pr + 16) * N + cc);
    floatx4 Q4 = *(const floatx4*)(psq + (size_t)pr * N + cc);
    Q4 += *(const floatx4*)(psq + (size_t)(pr + 16) * N + cc);
    ls[pr][t & 15] = S4;
    lq[pr][t & 15] = Q4;
  }
  __syncthreads();
  __shared__ floatx4 lA[16], lB[16];
  if (t < 16) {
    floatx4 S4 = {0.f, 0.f, 0.f, 0.f}, Q4 = {0.f, 0.f, 0.f, 0.f};
#pragma unroll
    for (int r = 0; r < 16; ++r) {
      S4 += ls[r][t];
      Q4 += lq[r][t];
    }
    floatx4 m = S4 * invM;
    floatx4 var = Q4 * invM - m * m;
    floatx4 rstd;
#pragma unroll
    for (int i = 0; i < 4; ++i) rstd[i] = rsqrtf(var[i] + 1e-5f);
    const int cc = cb * 64 + t * 4;
    floatx4 a = (*(const floatx4*)(g + cc)) * rstd;
    lA[t] = a;
    lB[t] = (*(const floatx4*)(be + cc)) - m * a;
  }
  __syncthreads();

  // phase 3: BN apply over own (L2-hot) Y block
  const floatx4 a = lA[cg], b2 = lB[cg];
  for (int r = r0 + rl; r < r0 + 128; r += 16) {
    size_t i = (size_t)r * N + col4;
    floatx4 v = (*(const floatx4*)(Y + i)) * a + b2;
    if (res) v += *(const floatx4*)(res + i);
#pragma unroll
    for (int ii = 0; ii < 4; ++ii) v[ii] = fmaxf(v[ii], 0.f);
    if (outf) *(floatx4*)(outf + i) = v;
    half4_t h, l;
#pragma unroll
    for (int ii = 0; ii < 4; ++ii) {
      _Float16 hh = (_Float16)v[ii];
      h[ii] = hh;
      l[ii] = (_Float16)((v[ii] - (float)hh) * LO_SCALE);
    }
    *(half4_t*)(oh + i) = h;
    *(half4_t*)(ol + i) = l;
  }
}

// ---- polar projection (== U@Vh from SVD) * sign(det), fused with head
//      split-K reduce + bias and the betas/camera tail copy ----
__device__ __forceinline__ void cofactor3(const float X[9], float C[9]) {
  C[0] = X[4] * X[8] - X[5] * X[7];
  C[1] = X[5] * X[6] - X[3] * X[8];
  C[2] = X[3] * X[7] - X[4] * X[6];
  C[3] = X[2] * X[7] - X[1] * X[8];
  C[4] = X[0] * X[8] - X[2] * X[6];
  C[5] = X[1] * X[6] - X[0] * X[7];
  C[6] = X[1] * X[5] - X[2] * X[4];
  C[7] = X[2] * X[3] - X[0] * X[5];
  C[8] = X[0] * X[4] - X[1] * X[3];
}

__global__ __launch_bounds__(256)
void polar_tail(const float* __restrict__ Cp, const float* __restrict__ bias,
                float* __restrict__ out, int Bt, int nmat, int S,
                size_t stride) {
  const int ldy = 256;
  int idx = blockIdx.x * blockDim.x + threadIdx.x;
  if (idx < nmat) {
    int s = idx / 24, j = idx % 24;
    const size_t base = (size_t)s * ldy + j * 9;
    float A[9], X[9];
#pragma unroll
    for (int k = 0; k < 9; ++k) {
      float v = bias[j * 9 + k];
      for (int z = 0; z < S; ++z) v += Cp[z * stride + base + k];
      A[k] = v;
      X[k] = v;
    }
    double detA = (double)A[0] * ((double)A[4] * A[8] - (double)A[5] * A[7]) -
                  (double)A[1] * ((double)A[3] * A[8] - (double)A[5] * A[6]) +
                  (double)A[2] * ((double)A[3] * A[7] - (double)A[4] * A[6]);
    float sgn = (detA < 0.0) ? -1.f : 1.f;
#pragma unroll 1
    for (int it = 0; it < 12; ++it) {
      float C[9];
      cofactor3(X, C);
      float det = X[0] * C[0] + X[1] * C[1] + X[2] * C[2];
      float ad = fmaxf(fabsf(det), 1e-30f);
      float idet = (det < 0.f ? -1.f : 1.f) / ad;
      float n1 = 0.f, n2 = 0.f;
#pragma unroll
      for (int k = 0; k < 9; ++k) {
        n1 += X[k] * X[k];
        n2 += C[k] * C[k];
      }
      n1 = fmaxf(n1, 1e-30f);
      float zeta = sqrtf(sqrtf(n2 * idet * idet / n1));
      zeta = fminf(fmaxf(zeta, 1e-4f), 1e4f);
      float iz = 0.5f / zeta;
      float hz = 0.5f * zeta;
#pragma unroll
      for (int k = 0; k < 9; ++k) X[k] = hz * X[k] + iz * idet * C[k];
    }
    float* o = out + (size_t)idx * 9;
#pragma unroll
    for (int k = 0; k < 9; ++k) o[k] = X[k] * sgn;
  } else {
    int i = idx - nmat;
    int nb = Bt * 10;
    int nc = Bt * 3;
    int s, k, c;
    if (i < nb) {
      s = i / 10;
      k = i;
      c = 216 + (i % 10);
    } else if (i < nb + nc) {
      int t2 = i - nb;
      s = t2 / 3;
      k = i;
      c = 226 + (t2 % 3);
    } else {
      return;
    }
    float v = bias[c];
    size_t base = (size_t)s * ldy + c;
    for (int z = 0; z < S; ++z) v += Cp[z * stride + base];
    out[(size_t)Bt * 216 + k] = v;
  }
}

// ---------------------------------------------------------------------------
extern "C" void kernel_launch(void* const* d_in, const int* in_sizes, int n_in,
                              void* d_out, int out_size, void* d_ws,
                              size_t ws_size, hipStream_t stream) {
  const float* x = (const float*)d_in[0];
  const float* w1 = (const float*)d_in[1];
  const float* b1 = (const float*)d_in[2];
  const float* g1 = (const float*)d_in[3];
  const float* be1 = (const float*)d_in[4];
  const float* w2a = (const float*)d_in[5];
  const float* b2a = (const float*)d_in[6];
  const float* g2a = (const float*)d_in[7];
  const float* be2a = (const float*)d_in[8];
  const float* w2b = (const float*)d_in[9];
  const float* b2b = (const float*)d_in[10];
  const float* g2b = (const float*)d_in[11];
  const float* be2b = (const float*)d_in[12];
  const float* w3a = (const float*)d_in[13];
  const float* b3a = (const float*)d_in[14];
  const float* g3a = (const float*)d_in[15];
  const float* be3a = (const float*)d_in[16];
  const float* w3b = (const float*)d_in[17];
  const float* b3b = (const float*)d_in[18];
  const float* g3b = (const float*)d_in[19];
  const float* be3b = (const float*)d_in[20];
  const float* w4 = (const float*)d_in[21];
  const float* b4 = (const float*)d_in[22];
  float* out = (float*)d_out;

  const int B = 4096, IN = 10338, INP = 10368, H = 1024;
  const int OUTN = 229, OUTP = 256;
  const int S_BIG = 2, S_MID = 2, S_HEAD = 8;

  char* p = (char*)d_ws;
  auto alloc = [&](size_t bytes) -> void* {
    void* r = (void*)p;
    p += (bytes + 255) & ~(size_t)255;
    return r;
  };
  float* Cpart = (float*)alloc((size_t)S_HEAD * B * OUTP * 4);  // 33.5 MB
  float* Y = (float*)alloc((size_t)B * H * 4);
  float* Hf = (float*)alloc((size_t)B * H * 4);
  _Float16* xh = (_Float16*)alloc((size_t)B * INP * 2);
  _Float16* xl = (_Float16*)alloc((size_t)B * INP * 2);
  _Float16* w1h = (_Float16*)alloc((size_t)H * INP * 2);
  _Float16* w1l = (_Float16*)alloc((size_t)H * INP * 2);
  _Float16 *wmh[4], *wml[4];
  for (int i = 0; i < 4; ++i) {
    wmh[i] = (_Float16*)alloc((size_t)H * H * 2);
    wml[i] = (_Float16*)alloc((size_t)H * H * 2);
  }
  _Float16* w4h = (_Float16*)alloc((size_t)OUTP * H * 2);
  _Float16* w4l = (_Float16*)alloc((size_t)OUTP * H * 2);
  _Float16* hh = (_Float16*)alloc((size_t)B * H * 2);
  _Float16* hl = (_Float16*)alloc((size_t)B * H * 2);
  float* psum = (float*)alloc((size_t)32 * H * 4);
  float* psq = (float*)alloc((size_t)32 * H * 4);
  int* counters = (int*)alloc(8 * sizeof(int));

  hipMemsetAsync(counters, 0, 8 * sizeof(int), stream);

  // ---- conversions (one kernel) ----
  {
    CJobs J;
    const float* wsrc[6] = {w1, w2a, w2b, w3a, w3b, w4};
    _Float16* th[6] = {w1h, wmh[0], wmh[1], wmh[2], wmh[3], w4h};
    _Float16* tl[6] = {w1l, wml[0], wml[1], wml[2], wml[3], w4l};
    int Ks[6] = {IN, H, H, H, H, H};
    int Ns[6] = {H, H, H, H, H, OUTN};
    int Kpads[6] = {INP, H, H, H, H, H};
    int Npads[6] = {H, H, H, H, H, OUTP};
    int start = 0;
    for (int i = 0; i < 6; ++i) {
      J.j[i].src = wsrc[i];
      J.j[i].th = th[i];
      J.j[i].tl = tl[i];
      J.j[i].K = Ks[i];
      J.j[i].N = Ns[i];
      J.j[i].Kpad = Kpads[i];
      J.j[i].tK = Kpads[i] / 32;
      J.j[i].start = start;
      start += (Kpads[i] / 32) * (Npads[i] / 32);
    }
    J.x = x;
    J.xh = xh;
    J.xl = xl;
    J.splitStart = start;
    int total = start + (B * INP / 8 + 255) / 256;
    convert_all<<<dim3(total), 256, 0, stream>>>(J);
  }

  auto reducebn = [&](const float* bias, int S, const float* g,
                      const float* be, const float* res, float* outf,
                      int layer) {
    reduce_bn_fused<<<dim3(16, 32), 256, 0, stream>>>(
        Cpart, bias, g, be, res, outf, hh, hl, Y, psum, psq, S, (size_t)B * H,
        counters + layer, 1.f / B);
  };

  // layer 1 (big)
  gemm_sk<0><<<dim3(B / 128, H / 128, S_BIG), 256, 0, stream>>>(
      xh, xl, w1h, w1l, Cpart, INP, H, INP / S_BIG, (size_t)B * H);
  reducebn(b1, S_BIG, g1, be1, nullptr, Hf, 0);
  // resblock 2
  gemm_sk<1><<<dim3(B / 128, H / 128, S_MID), 256, 0, stream>>>(
      hh, hl, wmh[0], wml[0], Cpart, H, H, H / S_MID, (size_t)B * H);
  reducebn(b2a, S_MID, g2a, be2a, nullptr, nullptr, 1);
  gemm_sk<1><<<dim3(B / 128, H / 128, S_MID), 256, 0, stream>>>(
      hh, hl, wmh[1], wml[1], Cpart, H, H, H / S_MID, (size_t)B * H);
  reducebn(b2b, S_MID, g2b, be2b, Hf, Hf, 2);
  // resblock 3
  gemm_sk<1><<<dim3(B / 128, H / 128, S_MID), 256, 0, stream>>>(
      hh, hl, wmh[2], wml[2], Cpart, H, H, H / S_MID, (size_t)B * H);
  reducebn(b3a, S_MID, g3a, be3a, nullptr, nullptr, 3);
  gemm_sk<1><<<dim3(B / 128, H / 128, S_MID), 256, 0, stream>>>(
      hh, hl, wmh[3], wml[3], Cpart, H, H, H / S_MID, (size_t)B * H);
  reducebn(b3b, S_MID, g3b, be3b, Hf, Hf, 4);
  // head
  gemm_sk<2><<<dim3(B / 128, OUTP / 128, S_HEAD), 256, 0, stream>>>(
      hh, hl, w4h, w4l, Cpart, H, OUTP, H / S_HEAD, (size_t)B * OUTP);

  int nmat = B * 24;
  int ntot = nmat + B * 13;
  polar_tail<<<dim3((ntot + 255) / 256), 256, 0, stream>>>(
      Cpart, b4, out, B, nmat, S_HEAD, (size_t)B * OUTP);
}

// Round 7
// 925.768 us; speedup vs baseline: 1.2844x; 1.2844x over previous
//
#include <hip/hip_runtime.h>
#include <math.h>

// ---------------------------------------------------------------------------
// B=4096, IN=10338 (pad 10368), H=1024, OUT=229 (pad 256)
// R7: f16x3 split-MFMA GEMM, R4-proven 3-D grids (XCD owns M-slice).
//     Mid GEMMs: S=1 with bias+column-stats fused into the epilogue
//     (LDS staging buffers reused as scratch) -> no reduce pass for mids.
//     Layer 1 keeps split-K + separate reduce; head reduce fused in polar.
//     NOTE (R6 lesson): in-kernel grid sync w/ agent fences = per-block L2
//     writeback on gfx950 -> ~50us/layer regression. Kernel boundaries win.
// ---------------------------------------------------------------------------

typedef _Float16 half8 __attribute__((ext_vector_type(8)));
typedef _Float16 half4_t __attribute__((ext_vector_type(4)));
typedef float floatx4 __attribute__((ext_vector_type(4)));

#define LO_SCALE 4096.0f
#define LO_INV (1.0f / 4096.0f)
#define IN_C 10338
#define INP_C 10368

__device__ __forceinline__ void gld16(const _Float16* g, _Float16* l) {
  __builtin_amdgcn_global_load_lds(
      (const __attribute__((address_space(1))) void*)g,
      (__attribute__((address_space(3))) void*)l, 16, 0, 0);
}

// C_partial[z] = A[M x Ks] * BT[N x Ks]^T  (f16 hi/lo, lo prescaled by 4096)
// grid (M/128, N/128, S); gid%8 == blockIdx.x%8 -> each XCD owns an M-slice
// (A locality: measured 344 MB vs 705 MB for N-sliced).
// STATS (requires S=1): epilogue adds bias, writes Y, and emits per-band
// column sum / sumsq partials (psum/psq[band][col]).
template <int TAG, bool STATS>
__global__ __launch_bounds__(256, 2)
void gemm_sk(const _Float16* __restrict__ Ah, const _Float16* __restrict__ Al,
             const _Float16* __restrict__ Bh, const _Float16* __restrict__ Bl,
             float* __restrict__ Cp, int Kld, int Ncols, int Ks,
             size_t partStride, const float* __restrict__ bias,
             float* __restrict__ psum, float* __restrict__ psq) {
  __shared__ _Float16 sAh[2][4096], sAl[2][4096];
  __shared__ _Float16 sBh[2][4096], sBl[2][4096];
  const int tid = threadIdx.x;
  const int wv = tid >> 6, ln = tid & 63;
  const int ln15 = ln & 15, q = ln >> 4;
  const int wr = wv >> 1, wc = wv & 1;
  const int bm0 = blockIdx.x * 128, bn0 = blockIdx.y * 128;
  const int k0 = blockIdx.z * Ks;
  Cp += (size_t)blockIdx.z * partStride;

  // staging: source-permuted so fixed lane->LDS placement yields XOR-swizzle
  const int srow = ln >> 2;
  const int swzw = (ln & 3) ^ (srow & 3) ^ ((srow >> 2) & 3);
  const int ch0 = wv * 2, ch1 = wv * 2 + 1;
  const size_t offA0 = (size_t)(bm0 + ch0 * 16 + srow) * Kld + k0 + swzw * 8;
  const size_t offA1 = (size_t)(bm0 + ch1 * 16 + srow) * Kld + k0 + swzw * 8;
  const size_t offB0 = (size_t)(bn0 + ch0 * 16 + srow) * Kld + k0 + swzw * 8;
  const size_t offB1 = (size_t)(bn0 + ch1 * 16 + srow) * Kld + k0 + swzw * 8;

  // fragment reads: de-swizzle
  const int swzr = (q ^ (ln15 & 3) ^ ((ln15 >> 2) & 3)) * 8;
  const int aoff = (wr * 64 + ln15) * 32 + swzr;
  const int boff = (wc * 64 + ln15) * 32 + swzr;

  floatx4 acc[4][4];
  floatx4 acc2[4][4];
#pragma unroll
  for (int i = 0; i < 4; ++i)
#pragma unroll
    for (int j = 0; j < 4; ++j) {
      acc[i][j] = (floatx4){0.f, 0.f, 0.f, 0.f};
      acc2[i][j] = (floatx4){0.f, 0.f, 0.f, 0.f};
    }

  auto stage = [&](int kt, int buf) {
    gld16(Ah + offA0 + kt, &sAh[buf][ch0 * 512]);
    gld16(Ah + offA1 + kt, &sAh[buf][ch1 * 512]);
    gld16(Al + offA0 + kt, &sAl[buf][ch0 * 512]);
    gld16(Al + offA1 + kt, &sAl[buf][ch1 * 512]);
    gld16(Bh + offB0 + kt, &sBh[buf][ch0 * 512]);
    gld16(Bh + offB1 + kt, &sBh[buf][ch1 * 512]);
    gld16(Bl + offB0 + kt, &sBl[buf][ch0 * 512]);
    gld16(Bl + offB1 + kt, &sBl[buf][ch1 * 512]);
  };

  stage(0, 0);
  int cur = 0;
  for (int kt = 0; kt < Ks; kt += 32) {
    __syncthreads();
    if (kt + 32 < Ks) stage(kt + 32, cur ^ 1);

    const _Float16* pAh = &sAh[cur][aoff];
    const _Float16* pAl = &sAl[cur][aoff];
    const _Float16* pBh = &sBh[cur][boff];
    const _Float16* pBl = &sBl[cur][boff];
    half8 bh[4], bl[4];
#pragma unroll
    for (int ni = 0; ni < 4; ++ni) {
      bh[ni] = *(const half8*)(pBh + ni * 512);
      bl[ni] = *(const half8*)(pBl + ni * 512);
    }
#pragma unroll
    for (int mh = 0; mh < 2; ++mh) {
      half8 ah[2], al[2];
#pragma unroll
      for (int i = 0; i < 2; ++i) {
        ah[i] = *(const half8*)(pAh + (mh * 2 + i) * 512);
        al[i] = *(const half8*)(pAl + (mh * 2 + i) * 512);
      }
#pragma unroll
      for (int i = 0; i < 2; ++i) {
        const int mi = mh * 2 + i;
#pragma unroll
        for (int ni = 0; ni < 4; ++ni) {
          acc[mi][ni] = __builtin_amdgcn_mfma_f32_16x16x32_f16(
              ah[i], bh[ni], acc[mi][ni], 0, 0, 0);
          acc2[mi][ni] = __builtin_amdgcn_mfma_f32_16x16x32_f16(
              ah[i], bl[ni], acc2[mi][ni], 0, 0, 0);
          acc2[mi][ni] = __builtin_amdgcn_mfma_f32_16x16x32_f16(
              al[i], bh[ni], acc2[mi][ni], 0, 0, 0);
        }
      }
    }
    cur ^= 1;
  }

  // C/D layout: col = lane&15, row = (lane>>4)*4 + reg  [m89-verified]
  float bs[4];
  float sacc[4] = {0.f, 0.f, 0.f, 0.f};
  float qacc[4] = {0.f, 0.f, 0.f, 0.f};
  if constexpr (STATS) {
#pragma unroll
    for (int ni = 0; ni < 4; ++ni)
      bs[ni] = bias[bn0 + wc * 64 + ni * 16 + ln15];
  }
#pragma unroll
  for (int mi = 0; mi < 4; ++mi)
#pragma unroll
    for (int ni = 0; ni < 4; ++ni) {
      const int col = bn0 + wc * 64 + ni * 16 + ln15;
      const int rbase = bm0 + wr * 64 + mi * 16 + q * 4;
#pragma unroll
      for (int r = 0; r < 4; ++r) {
        float v = acc[mi][ni][r] + acc2[mi][ni][r] * LO_INV;
        if constexpr (STATS) {
          v += bs[ni];
          sacc[ni] += v;
          qacc[ni] += v * v;
        }
        Cp[(size_t)(rbase + r) * Ncols + col] = v;
      }
    }
  if constexpr (STATS) {
    // reuse staging LDS as scratch: 8 contributors x 128 cols
    __syncthreads();  // all waves done reading staging LDS
    float* sS = (float*)&sAh[0][0];
    float* sQ = (float*)&sAl[0][0];
    const int contrib = wr * 4 + q;  // 0..7
#pragma unroll
    for (int ni = 0; ni < 4; ++ni) {
      const int colt = wc * 64 + ni * 16 + ln15;
      sS[contrib * 128 + colt] = sacc[ni];
      sQ[contrib * 128 + colt] = qacc[ni];
    }
    __syncthreads();
    if (tid < 128) {
      float S = 0.f, Q = 0.f;
#pragma unroll
      for (int c = 0; c < 8; ++c) {
        S += sS[c * 128 + tid];
        Q += sQ[c * 128 + tid];
      }
      psum[(size_t)blockIdx.x * 1024 + bn0 + tid] = S;
      psq[(size_t)blockIdx.x * 1024 + bn0 + tid] = Q;
    }
  }
}

// ---- all conversions in one kernel ----
struct TJob {
  const float* src;
  _Float16* th;
  _Float16* tl;
  int K, N, Kpad, tK, start;
};
struct CJobs {
  TJob j[6];
  const float* x;
  _Float16* xh;
  _Float16* xl;
  int splitStart;
};

__global__ __launch_bounds__(256)
void convert_all(CJobs J) {
  const int b = blockIdx.x;
  const int tid = threadIdx.x;
  if (b >= J.splitStart) {
    int di = (b - J.splitStart) * 256 + tid;
    int base = di * 8;
    int row = base / INP_C;
    int col0 = base - row * INP_C;
    const float* src = J.x + (size_t)row * IN_C + col0;
    float v[8];
#pragma unroll
    for (int j = 0; j < 8; ++j) v[j] = (col0 + j < IN_C) ? src[j] : 0.f;
    half8 h, l;
#pragma unroll
    for (int j = 0; j < 8; ++j) {
      _Float16 hh = (_Float16)v[j];
      h[j] = hh;
      l[j] = (_Float16)((v[j] - (float)hh) * LO_SCALE);
    }
    *(half8*)(J.xh + base) = h;
    *(half8*)(J.xl + base) = l;
    return;
  }
  int ji = 0;
#pragma unroll
  for (int i = 1; i < 6; ++i)
    if (b >= J.j[i].start) ji = i;
  const TJob job = J.j[ji];
  const int t = b - job.start;
  const int kk0 = (t % job.tK) * 32;
  const int nn0 = (t / job.tK) * 32;

  __shared__ float ts[32][33];
  const int tx = tid & 31, ty = tid >> 5;
#pragma unroll
  for (int r = 0; r < 4; ++r) {
    int kk = kk0 + ty + r * 8;
    int nn = nn0 + tx;
    ts[ty + r * 8][tx] =
        (kk < job.K && nn < job.N) ? job.src[(size_t)kk * job.N + nn] : 0.f;
  }
  __syncthreads();
  const int tw = tid & 7, rw = tid >> 3;
  const int nn = nn0 + rw, kk = kk0 + tw * 4;
  half4_t h, l;
#pragma unroll
  for (int i2 = 0; i2 < 4; ++i2) {
    float v = ts[tw * 4 + i2][rw];
    _Float16 hh = (_Float16)v;
    h[i2] = hh;
    l[i2] = (_Float16)((v - (float)hh) * LO_SCALE);
  }
  size_t o = (size_t)nn * job.Kpad + kk;
  *(half4_t*)(job.th + o) = h;
  *(half4_t*)(job.tl + o) = l;
}

// ---- layer-1: sum split-K partials + bias -> Y, per-rowband col stats ----
// grid (16, 32) = 512 blocks; block = 16 colgroups(x4 cols) x 16 rowlanes
__global__ __launch_bounds__(256)
void reduce_bias_stats_v(const float* __restrict__ Cp,
                         const float* __restrict__ bias, float* __restrict__ Y,
                         float* __restrict__ psum, float* __restrict__ psq,
                         int S, size_t stride, int rowsPer) {
  const int N = 1024;
  const int t = threadIdx.x;
  const int cg = t & 15, rl = t >> 4;
  const int col4 = blockIdx.x * 64 + cg * 4;
  const int r0 = blockIdx.y * rowsPer;
  const floatx4 bs = *(const floatx4*)(bias + col4);
  floatx4 s = {0.f, 0.f, 0.f, 0.f}, qq = {0.f, 0.f, 0.f, 0.f};
  for (int r = r0 + rl; r < r0 + rowsPer; r += 16) {
    size_t i = (size_t)r * N + col4;
    floatx4 v = bs;
    for (int k = 0; k < S; ++k) v += *(const floatx4*)(Cp + k * stride + i);
    *(floatx4*)(Y + i) = v;
    s += v;
    qq += v * v;
  }
  __shared__ floatx4 ls[16][16], lq[16][16];
  ls[rl][cg] = s;
  lq[rl][cg] = qq;
  __syncthreads();
  if (t < 16) {
    floatx4 S4 = {0.f, 0.f, 0.f, 0.f}, Q4 = {0.f, 0.f, 0.f, 0.f};
#pragma unroll
    for (int r = 0; r < 16; ++r) {
      S4 += ls[r][t];
      Q4 += lq[r][t];
    }
    size_t o = (size_t)blockIdx.y * N + blockIdx.x * 64 + t * 4;
    *(floatx4*)(psum + o) = S4;
    *(floatx4*)(psq + o) = Q4;
  }
}

// ---- BN finalize+apply (+res, relu) + f16 hi/lo split; float4/half4 ----
__global__ __launch_bounds__(256)
void bn_apply_v(const float* __restrict__ Y, const float* __restrict__ psum,
                const float* __restrict__ psq, const float* __restrict__ g,
                const float* __restrict__ be, const float* __restrict__ res,
                float* __restrict__ outf, _Float16* __restrict__ oh,
                _Float16* __restrict__ ol, int RB, float invM) {
  const int N = 1024;
  const int t = threadIdx.x;
  const int cg = t & 63, rl = t >> 6;
  const int col4 = blockIdx.x * 256 + cg * 4;
  __shared__ floatx4 lA[64], lB[64];
  if (t < 64) {
    int c4 = blockIdx.x * 256 + t * 4;
    floatx4 s = {0.f, 0.f, 0.f, 0.f}, qq = {0.f, 0.f, 0.f, 0.f};
    for (int rb = 0; rb < RB; ++rb) {
      s += *(const floatx4*)(psum + (size_t)rb * N + c4);
      qq += *(const floatx4*)(psq + (size_t)rb * N + c4);
    }
    floatx4 m = s * invM;
    floatx4 var = qq * invM - m * m;
    floatx4 rstd;
#pragma unroll
    for (int i = 0; i < 4; ++i) rstd[i] = rsqrtf(var[i] + 1e-5f);
    floatx4 a = (*(const floatx4*)(g + c4)) * rstd;
    lA[t] = a;
    lB[t] = (*(const floatx4*)(be + c4)) - m * a;
  }
  __syncthreads();
  const floatx4 a = lA[cg], b2 = lB[cg];
#pragma unroll
  for (int rr = 0; rr < 2; ++rr) {
    const int r = blockIdx.y * 8 + rl + rr * 4;
    const size_t i = (size_t)r * N + col4;
    floatx4 v = (*(const floatx4*)(Y + i)) * a + b2;
    if (res) v += *(const floatx4*)(res + i);
#pragma unroll
    for (int ii = 0; ii < 4; ++ii) v[ii] = fmaxf(v[ii], 0.f);
    if (outf) *(floatx4*)(outf + i) = v;
    half4_t h, l;
#pragma unroll
    for (int ii = 0; ii < 4; ++ii) {
      _Float16 hh = (_Float16)v[ii];
      h[ii] = hh;
      l[ii] = (_Float16)((v[ii] - (float)hh) * LO_SCALE);
    }
    *(half4_t*)(oh + i) = h;
    *(half4_t*)(ol + i) = l;
  }
}

// ---- polar projection (== U@Vh from SVD) * sign(det), fused with head
//      split-K reduce + bias and the betas/camera tail copy ----
__device__ __forceinline__ void cofactor3(const float X[9], float C[9]) {
  C[0] = X[4] * X[8] - X[5] * X[7];
  C[1] = X[5] * X[6] - X[3] * X[8];
  C[2] = X[3] * X[7] - X[4] * X[6];
  C[3] = X[2] * X[7] - X[1] * X[8];
  C[4] = X[0] * X[8] - X[2] * X[6];
  C[5] = X[1] * X[6] - X[0] * X[7];
  C[6] = X[1] * X[5] - X[2] * X[4];
  C[7] = X[2] * X[3] - X[0] * X[5];
  C[8] = X[0] * X[4] - X[1] * X[3];
}

__global__ __launch_bounds__(256)
void polar_tail(const float* __restrict__ Cp, const float* __restrict__ bias,
                float* __restrict__ out, int Bt, int nmat, int S,
                size_t stride) {
  const int ldy = 256;
  int idx = blockIdx.x * blockDim.x + threadIdx.x;
  if (idx < nmat) {
    int s = idx / 24, j = idx % 24;
    const size_t base = (size_t)s * ldy + j * 9;
    float A[9], X[9];
#pragma unroll
    for (int k = 0; k < 9; ++k) {
      float v = bias[j * 9 + k];
      for (int z = 0; z < S; ++z) v += Cp[z * stride + base + k];
      A[k] = v;
      X[k] = v;
    }
    double detA = (double)A[0] * ((double)A[4] * A[8] - (double)A[5] * A[7]) -
                  (double)A[1] * ((double)A[3] * A[8] - (double)A[5] * A[6]) +
                  (double)A[2] * ((double)A[3] * A[7] - (double)A[4] * A[6]);
    float sgn = (detA < 0.0) ? -1.f : 1.f;
#pragma unroll 1
    for (int it = 0; it < 12; ++it) {
      float C[9];
      cofactor3(X, C);
      float det = X[0] * C[0] + X[1] * C[1] + X[2] * C[2];
      float ad = fmaxf(fabsf(det), 1e-30f);
      float idet = (det < 0.f ? -1.f : 1.f) / ad;
      float n1 = 0.f, n2 = 0.f;
#pragma unroll
      for (int k = 0; k < 9; ++k) {
        n1 += X[k] * X[k];
        n2 += C[k] * C[k];
      }
      n1 = fmaxf(n1, 1e-30f);
      float zeta = sqrtf(sqrtf(n2 * idet * idet / n1));
      zeta = fminf(fmaxf(zeta, 1e-4f), 1e4f);
      float iz = 0.5f / zeta;
      float hz = 0.5f * zeta;
#pragma unroll
      for (int k = 0; k < 9; ++k) X[k] = hz * X[k] + iz * idet * C[k];
    }
    float* o = out + (size_t)idx * 9;
#pragma unroll
    for (int k = 0; k < 9; ++k) o[k] = X[k] * sgn;
  } else {
    int i = idx - nmat;
    int nb = Bt * 10;
    int nc = Bt * 3;
    int s, k, c;
    if (i < nb) {
      s = i / 10;
      k = i;
      c = 216 + (i % 10);
    } else if (i < nb + nc) {
      int t2 = i - nb;
      s = t2 / 3;
      k = i;
      c = 226 + (t2 % 3);
    } else {
      return;
    }
    float v = bias[c];
    size_t base = (size_t)s * ldy + c;
    for (int z = 0; z < S; ++z) v += Cp[z * stride + base];
    out[(size_t)Bt * 216 + k] = v;
  }
}

// ---------------------------------------------------------------------------
extern "C" void kernel_launch(void* const* d_in, const int* in_sizes, int n_in,
                              void* d_out, int out_size, void* d_ws,
                              size_t ws_size, hipStream_t stream) {
  const float* x = (const float*)d_in[0];
  const float* w1 = (const float*)d_in[1];
  const float* b1 = (const float*)d_in[2];
  const float* g1 = (const float*)d_in[3];
  const float* be1 = (const float*)d_in[4];
  const float* w2a = (const float*)d_in[5];
  const float* b2a = (const float*)d_in[6];
  const float* g2a = (const float*)d_in[7];
  const float* be2a = (const float*)d_in[8];
  const float* w2b = (const float*)d_in[9];
  const float* b2b = (const float*)d_in[10];
  const float* g2b = (const float*)d_in[11];
  const float* be2b = (const float*)d_in[12];
  const float* w3a = (const float*)d_in[13];
  const float* b3a = (const float*)d_in[14];
  const float* g3a = (const float*)d_in[15];
  const float* be3a = (const float*)d_in[16];
  const float* w3b = (const float*)d_in[17];
  const float* b3b = (const float*)d_in[18];
  const float* g3b = (const float*)d_in[19];
  const float* be3b = (const float*)d_in[20];
  const float* w4 = (const float*)d_in[21];
  const float* b4 = (const float*)d_in[22];
  float* out = (float*)d_out;

  const int B = 4096, IN = 10338, INP = 10368, H = 1024;
  const int OUTN = 229, OUTP = 256;
  const int RB = 32;
  const int S_BIG = 2, S_HEAD = 8;

  char* p = (char*)d_ws;
  auto alloc = [&](size_t bytes) -> void* {
    void* r = (void*)p;
    p += (bytes + 255) & ~(size_t)255;
    return r;
  };
  float* Cpart = (float*)alloc((size_t)S_HEAD * B * OUTP * 4);  // 33.5 MB
  float* Y = (float*)alloc((size_t)B * H * 4);
  float* Hf = (float*)alloc((size_t)B * H * 4);
  _Float16* xh = (_Float16*)alloc((size_t)B * INP * 2);
  _Float16* xl = (_Float16*)alloc((size_t)B * INP * 2);
  _Float16* w1h = (_Float16*)alloc((size_t)H * INP * 2);
  _Float16* w1l = (_Float16*)alloc((size_t)H * INP * 2);
  _Float16 *wmh[4], *wml[4];
  for (int i = 0; i < 4; ++i) {
    wmh[i] = (_Float16*)alloc((size_t)H * H * 2);
    wml[i] = (_Float16*)alloc((size_t)H * H * 2);
  }
  _Float16* w4h = (_Float16*)alloc((size_t)OUTP * H * 2);
  _Float16* w4l = (_Float16*)alloc((size_t)OUTP * H * 2);
  _Float16* hh = (_Float16*)alloc((size_t)B * H * 2);
  _Float16* hl = (_Float16*)alloc((size_t)B * H * 2);
  float* psum = (float*)alloc((size_t)RB * H * 4);
  float* psq = (float*)alloc((size_t)RB * H * 4);

  // ---- conversions (one kernel) ----
  {
    CJobs J;
    const float* wsrc[6] = {w1, w2a, w2b, w3a, w3b, w4};
    _Float16* th[6] = {w1h, wmh[0], wmh[1], wmh[2], wmh[3], w4h};
    _Float16* tl[6] = {w1l, wml[0], wml[1], wml[2], wml[3], w4l};
    int Ks[6] = {IN, H, H, H, H, H};
    int Ns[6] = {H, H, H, H, H, OUTN};
    int Kpads[6] = {INP, H, H, H, H, H};
    int Npads[6] = {H, H, H, H, H, OUTP};
    int start = 0;
    for (int i = 0; i < 6; ++i) {
      J.j[i].src = wsrc[i];
      J.j[i].th = th[i];
      J.j[i].tl = tl[i];
      J.j[i].K = Ks[i];
      J.j[i].N = Ns[i];
      J.j[i].Kpad = Kpads[i];
      J.j[i].tK = Kpads[i] / 32;
      J.j[i].start = start;
      start += (Kpads[i] / 32) * (Npads[i] / 32);
    }
    J.x = x;
    J.xh = xh;
    J.xl = xl;
    J.splitStart = start;
    int total = start + (B * INP / 8 + 255) / 256;
    convert_all<<<dim3(total), 256, 0, stream>>>(J);
  }

  auto bnapply = [&](const float* g, const float* be, const float* res,
                     float* outf) {
    bn_apply_v<<<dim3(H / 256, B / 8), 256, 0, stream>>>(
        Y, psum, psq, g, be, res, outf, hh, hl, RB, 1.f / B);
  };
  // mid GEMM: S=1, bias+stats fused in epilogue, writes Y directly
  auto midgemm = [&](const _Float16* Bh, const _Float16* Bl,
                     const float* bias) {
    gemm_sk<1, true><<<dim3(B / 128, H / 128, 1), 256, 0, stream>>>(
        hh, hl, Bh, Bl, Y, H, H, H, 0, bias, psum, psq);
  };

  // layer 1 (big): split-K=2 + separate reduce
  gemm_sk<0, false><<<dim3(B / 128, H / 128, S_BIG), 256, 0, stream>>>(
      xh, xl, w1h, w1l, Cpart, INP, H, INP / S_BIG, (size_t)B * H, nullptr,
      nullptr, nullptr);
  reduce_bias_stats_v<<<dim3(16, RB), 256, 0, stream>>>(
      Cpart, b1, Y, psum, psq, S_BIG, (size_t)B * H, B / RB);
  bnapply(g1, be1, nullptr, Hf);
  // resblock 2
  midgemm(wmh[0], wml[0], b2a);
  bnapply(g2a, be2a, nullptr, nullptr);
  midgemm(wmh[1], wml[1], b2b);
  bnapply(g2b, be2b, Hf, Hf);
  // resblock 3
  midgemm(wmh[2], wml[2], b3a);
  bnapply(g3a, be3a, nullptr, nullptr);
  midgemm(wmh[3], wml[3], b3b);
  bnapply(g3b, be3b, Hf, Hf);
  // head: split-K=8, reduce fused into polar_tail
  gemm_sk<2, false><<<dim3(B / 128, OUTP / 128, S_HEAD), 256, 0, stream>>>(
      hh, hl, w4h, w4l, Cpart, H, OUTP, H / S_HEAD, (size_t)B * OUTP, nullptr,
      nullptr, nullptr);

  int nmat = B * 24;
  int ntot = nmat + B * 13;
  polar_tail<<<dim3((ntot + 255) / 256), 256, 0, stream>>>(
      Cpart, b4, out, B, nmat, S_HEAD, (size_t)B * OUTP);
}